// Round 1
// baseline (136.319 us; speedup 1.0000x reference)
//
#include <hip/hip_runtime.h>
#include <math.h>

// TTMultiheadAttention simplified:
//   final[b,s,d] = sum_i (1/l_i) * sum_e exp2(cA2_i * g_i[e]) * cr[b,e]
//   g_i[e] = sum_q br[i,e,q] * x[q,s,d]
//   cA2_i  = (sum_k ar[0,k,i]) / sqrt(32) * log2(e)
//   l_i    = sum_e exp2(cA2_i * g_i[e])
// One thread per (s,d); e is the sequential axis. br/cr reads are
// wave-uniform -> scalar loads on the SMEM pipe.

#define SS 512
#define DD 256
#define R2 16
#define R1 3

__global__ __launch_bounds__(256, 2) void tt_attn_kernel(
    const float* __restrict__ x,
    const float* __restrict__ ar,
    const float* __restrict__ br,
    const float* __restrict__ cr,
    float* __restrict__ out)
{
    const int s = blockIdx.x;
    const int d = threadIdx.x;

    // cA2_i = (sum_k ar[0,k,i]) * (1/sqrt(32)) * log2(e)
    float cA2[R1];
#pragma unroll
    for (int i = 0; i < R1; ++i) {
        float A = ar[0 * 3 + i] + ar[1 * 3 + i] + ar[2 * 3 + i];
        cA2[i] = A * (0.17677669529663687f * 1.4426950408889634f);
    }

    // v[q] = x[q, s, d]  (coalesced across threads: consecutive d)
    float v[R2];
#pragma unroll
    for (int q = 0; q < R2; ++q)
        v[q] = x[(q * SS + s) * DD + d];

    float l[R1] = {0.f, 0.f, 0.f};
    float acc[R1][R2];
#pragma unroll
    for (int i = 0; i < R1; ++i)
#pragma unroll
        for (int b = 0; b < R2; ++b) acc[i][b] = 0.f;

    for (int e = 0; e < DD; ++e) {
        float p[R1];
#pragma unroll
        for (int i = 0; i < R1; ++i) {
            const float* brp = br + (i * DD + e) * R2;  // uniform addr -> s_load
            float g = 0.f;
#pragma unroll
            for (int q = 0; q < R2; ++q) g = fmaf(brp[q], v[q], g);
            p[i] = exp2f(cA2[i] * g);
            l[i] += p[i];
        }
#pragma unroll
        for (int b = 0; b < R2; ++b) {
            float c = cr[b * DD + e];  // uniform addr -> s_load
#pragma unroll
            for (int i = 0; i < R1; ++i)
                acc[i][b] = fmaf(p[i], c, acc[i][b]);
        }
    }

    float il[R1];
#pragma unroll
    for (int i = 0; i < R1; ++i) il[i] = 1.0f / l[i];

#pragma unroll
    for (int b = 0; b < R2; ++b) {
        float o = acc[0][b] * il[0] + acc[1][b] * il[1] + acc[2][b] * il[2];
        out[(b * SS + s) * DD + d] = o;
    }
}

extern "C" void kernel_launch(void* const* d_in, const int* in_sizes, int n_in,
                              void* d_out, int out_size, void* d_ws, size_t ws_size,
                              hipStream_t stream) {
    const float* x  = (const float*)d_in[0];
    const float* ar = (const float*)d_in[1];
    const float* br = (const float*)d_in[2];
    const float* cr = (const float*)d_in[3];
    float* out = (float*)d_out;

    dim3 grid(SS);
    dim3 block(DD);
    hipLaunchKernelGGL(tt_attn_kernel, grid, block, 0, stream, x, ar, br, cr, out);
}